// Round 1
// baseline (3042.065 us; speedup 1.0000x reference)
//
#include <hip/hip_runtime.h>

// Problem constants (match reference setup_inputs)
constexpr int NN = 50000;        // nodes
constexpr int NE = 1600000;      // edges
constexpr int NB = 8;            // batch
constexpr int M_ROWS = NN * NB;  // 400000 flattened rows (m = b*NN + n)

// ---------------------------------------------------------------------------
// CSR row_ptr from sorted edge_rows via per-row binary search (lower_bound).
// ---------------------------------------------------------------------------
__global__ __launch_bounds__(256) void rowptr_kernel(const int* __restrict__ rows,
                                                     int* __restrict__ row_ptr) {
  const int r = blockIdx.x * 256 + threadIdx.x;
  if (r > NN) return;
  int lo = 0, hi = NE;
  while (lo < hi) {
    const int mid = (lo + hi) >> 1;
    if (rows[mid] < r) lo = mid + 1;
    else hi = mid;
  }
  row_ptr[r] = lo;
}

// ---------------------------------------------------------------------------
// Tall-skinny fp32 GEMM: S[M][DOUT] = A[M][128] @ W[128][DOUT]
// 128-row x DOUT-col tile per block, 256 threads, 8x(DOUT/16) register tile.
// As stored k-major with stride 129 (conflict-free scalar reads/writes).
// ---------------------------------------------------------------------------
template <int DOUT>
__global__ __launch_bounds__(256) void gemm_kernel(const float* __restrict__ A,
                                                   const float* __restrict__ W,
                                                   float* __restrict__ S) {
  constexpr int KC = 32;
  constexpr int CPT = DOUT / 16;  // cols per thread: 8 (DOUT=128) or 4 (DOUT=64)
  __shared__ float As[KC][129];
  __shared__ float Ws[KC][DOUT];

  const int t = threadIdx.x;
  const int ty = t >> 4;          // 0..15 -> row groups
  const int tx = t & 15;          // 0..15 -> col groups
  const size_t m0 = (size_t)blockIdx.x * 128;

  float acc[8][CPT];
#pragma unroll
  for (int i = 0; i < 8; i++)
#pragma unroll
    for (int jj = 0; jj < CPT; jj++) acc[i][jj] = 0.f;

  const int mload = t >> 3;        // 0..31
  const int kf = (t & 7) << 2;     // 0,4,...,28

  for (int kc = 0; kc < 128; kc += KC) {
    // stage A tile (128 rows x 32 k), transposed into As[k][m]
#pragma unroll
    for (int q = 0; q < 4; q++) {
      const int m = mload + 32 * q;
      const float4 g = *(const float4*)(A + (m0 + m) * 128 + kc + kf);
      As[kf + 0][m] = g.x;
      As[kf + 1][m] = g.y;
      As[kf + 2][m] = g.z;
      As[kf + 3][m] = g.w;
    }
    // stage W tile (32 k x DOUT cols)
#pragma unroll
    for (int q = 0; q < (KC * DOUT) / 1024; q++) {
      const int idx = (t + q * 256) << 2;
      const int kk = idx / DOUT;
      const int j = idx % DOUT;
      *(float4*)(&Ws[kk][j]) = *(const float4*)(W + (size_t)(kc + kk) * DOUT + j);
    }
    __syncthreads();

#pragma unroll
    for (int kk = 0; kk < KC; kk++) {
      float a[8], w[CPT];
#pragma unroll
      for (int v = 0; v < 4; v++) {
        a[v] = As[kk][ty * 4 + v];
        a[4 + v] = As[kk][64 + ty * 4 + v];
      }
#pragma unroll
      for (int v = 0; v < 4; v++) {
        w[v] = Ws[kk][tx * 4 + v];
        if constexpr (CPT == 8) w[4 + v] = Ws[kk][64 + tx * 4 + v];
      }
#pragma unroll
      for (int i = 0; i < 8; i++)
#pragma unroll
        for (int jj = 0; jj < CPT; jj++) acc[i][jj] += a[i] * w[jj];
    }
    __syncthreads();
  }

  // store: rows {ty*4+v, 64+ty*4+v}, cols {tx*4+v} (and +64 for DOUT=128)
#pragma unroll
  for (int i = 0; i < 8; i++) {
    const int m = (i < 4) ? (ty * 4 + i) : (64 + ty * 4 + (i - 4));
    float* orow = S + (m0 + m) * DOUT;
    float4 o;
    o.x = acc[i][0]; o.y = acc[i][1]; o.z = acc[i][2]; o.w = acc[i][3];
    *(float4*)(orow + tx * 4) = o;
    if constexpr (CPT == 8) {
      float4 o2;
      o2.x = acc[i][4]; o2.y = acc[i][5]; o2.z = acc[i][6]; o2.w = acc[i][7];
      *(float4*)(orow + 64 + tx * 4) = o2;
    }
  }
}

// ---------------------------------------------------------------------------
// SpMM + bias + (residual) + relu + (sigmoid).
// One block per destination row r; 256 threads own all NB*DOUT outputs
// (VEC floats each). Edges staged through LDS; per edge one coalesced
// NB*DOUT*4-byte gather (8 x DOUT*4B segments across batches).
// out/resid deliberately NOT __restrict__ (layer 2 runs in-place).
// ---------------------------------------------------------------------------
template <int DOUT, bool RESID, bool SIGMOID>
__global__ __launch_bounds__(256) void spmm_kernel(const float* __restrict__ S,
                                                   const int* __restrict__ row_ptr,
                                                   const int* __restrict__ cols,
                                                   const float* __restrict__ vals,
                                                   const float* __restrict__ bias,
                                                   const float* resid,
                                                   float* out) {
  constexpr int VEC = (NB * DOUT) / 256;  // 4 (DOUT=128) or 2 (DOUT=64)
  typedef float vec_t __attribute__((ext_vector_type(VEC)));

  const int r = blockIdx.x;
  const int t = threadIdx.x;
  const int idx = t * VEC;
  const int b = idx / DOUT;
  const int j = idx % DOUT;
  const size_t batch_off = (size_t)b * NN * DOUT + j;  // add c*DOUT for column c

  vec_t acc;
#pragma unroll
  for (int v = 0; v < VEC; v++) acc[v] = 0.f;

  __shared__ int sc[256];
  __shared__ float sv[256];

  const int e0 = row_ptr[r];
  const int e1 = row_ptr[r + 1];

  for (int e = e0; e < e1; e += 256) {
    const int chunk = min(256, e1 - e);
    __syncthreads();
    if (t < chunk) {
      sc[t] = cols[e + t];
      sv[t] = vals[e + t];
    }
    __syncthreads();
    int i = 0;
    for (; i + 4 <= chunk; i += 4) {
      const vec_t g0 = *(const vec_t*)(S + batch_off + (size_t)sc[i + 0] * DOUT);
      const vec_t g1 = *(const vec_t*)(S + batch_off + (size_t)sc[i + 1] * DOUT);
      const vec_t g2 = *(const vec_t*)(S + batch_off + (size_t)sc[i + 2] * DOUT);
      const vec_t g3 = *(const vec_t*)(S + batch_off + (size_t)sc[i + 3] * DOUT);
      acc += sv[i + 0] * g0;
      acc += sv[i + 1] * g1;
      acc += sv[i + 2] * g2;
      acc += sv[i + 3] * g3;
    }
    for (; i < chunk; i++) {
      const vec_t g = *(const vec_t*)(S + batch_off + (size_t)sc[i] * DOUT);
      acc += sv[i] * g;
    }
  }

  // epilogue
  const size_t orow = batch_off + (size_t)r * DOUT;  // == (b*NN + r)*DOUT + j
  const vec_t bb = *(const vec_t*)(bias + j);
  acc += bb;
  if constexpr (RESID) {
    const vec_t res = *(const vec_t*)(resid + orow);
    acc += res;
  }
#pragma unroll
  for (int v = 0; v < VEC; v++) {
    float o = fmaxf(acc[v], 0.f);
    if constexpr (SIGMOID) o = 1.f / (1.f + __expf(-o));
    acc[v] = o;
  }
  *(vec_t*)(out + orow) = acc;
}

// ---------------------------------------------------------------------------
// Launch: rowptr, then 3x (gemm -> spmm). Ping-pong buffers in d_ws.
//   bufA: support S (written by gemm, gathered by spmm)
//   bufB: layer activations H (spmm output; layer-2 updates it in place)
// ws usage: 256 KiB + 2 * 204.8 MB ~= 410 MB.
// ---------------------------------------------------------------------------
extern "C" void kernel_launch(void* const* d_in, const int* in_sizes, int n_in,
                              void* d_out, int out_size, void* d_ws, size_t ws_size,
                              hipStream_t stream) {
  const float* x = (const float*)d_in[0];
  const int* erows = (const int*)d_in[1];
  const int* ecols = (const int*)d_in[2];
  const float* evals = (const float*)d_in[3];
  const float* W1 = (const float*)d_in[4];
  const float* b1 = (const float*)d_in[5];
  const float* W2 = (const float*)d_in[6];
  const float* b2 = (const float*)d_in[7];
  const float* W3 = (const float*)d_in[8];
  const float* b3 = (const float*)d_in[9];

  char* ws = (char*)d_ws;
  int* row_ptr = (int*)ws;
  float* bufA = (float*)(ws + (1 << 18));
  float* bufB = (float*)(ws + (1 << 18) + (size_t)M_ROWS * 128 * 4);

  rowptr_kernel<<<(NN + 256) / 256, 256, 0, stream>>>(erows, row_ptr);

  // Layer 1: S = x@W1; H1 = relu(spmm(S) + b1 + x)
  gemm_kernel<128><<<M_ROWS / 128, 256, 0, stream>>>(x, W1, bufA);
  spmm_kernel<128, true, false><<<NN, 256, 0, stream>>>(bufA, row_ptr, ecols, evals,
                                                        b1, x, bufB);
  // Layer 2: S = H1@W2; H2 = relu(spmm(S) + b2 + H1)  (in place on bufB)
  gemm_kernel<128><<<M_ROWS / 128, 256, 0, stream>>>(bufB, W2, bufA);
  spmm_kernel<128, true, false><<<NN, 256, 0, stream>>>(bufA, row_ptr, ecols, evals,
                                                        b2, bufB, bufB);
  // Layer 3: S = H2@W3; out = sigmoid(relu(spmm(S) + b3))
  gemm_kernel<64><<<M_ROWS / 128, 256, 0, stream>>>(bufB, W3, bufA);
  spmm_kernel<64, false, true><<<NN, 256, 0, stream>>>(bufA, row_ptr, ecols, evals,
                                                       b3, nullptr, (float*)d_out);
}

// Round 2
// 2687.433 us; speedup vs baseline: 1.1320x; 1.1320x over previous
//
#include <hip/hip_runtime.h>

// Problem constants (match reference setup_inputs)
constexpr int NN = 50000;        // nodes
constexpr int NE = 1600000;      // edges
constexpr int NB = 8;            // batch
constexpr int M_ROWS = NN * NB;  // 400000 flattened rows (m = b*NN + n)

// ---------------------------------------------------------------------------
// CSR row_ptr from sorted edge_rows via per-row binary search (lower_bound).
// ---------------------------------------------------------------------------
__global__ __launch_bounds__(256) void rowptr_kernel(const int* __restrict__ rows,
                                                     int* __restrict__ row_ptr) {
  const int r = blockIdx.x * 256 + threadIdx.x;
  if (r > NN) return;
  int lo = 0, hi = NE;
  while (lo < hi) {
    const int mid = (lo + hi) >> 1;
    if (rows[mid] < r) lo = mid + 1;
    else hi = mid;
  }
  row_ptr[r] = lo;
}

// ---------------------------------------------------------------------------
// Tall-skinny fp32 GEMM: S[M][DOUT] = A[M][128] @ W[128][DOUT]
// 128-row x DOUT-col tile per block, 256 threads, 8x(DOUT/16) register tile.
// ---------------------------------------------------------------------------
template <int DOUT>
__global__ __launch_bounds__(256) void gemm_kernel(const float* __restrict__ A,
                                                   const float* __restrict__ W,
                                                   float* __restrict__ S) {
  constexpr int KC = 32;
  constexpr int CPT = DOUT / 16;  // cols per thread: 8 (DOUT=128) or 4 (DOUT=64)
  __shared__ float As[KC][129];
  __shared__ float Ws[KC][DOUT];

  const int t = threadIdx.x;
  const int ty = t >> 4;          // 0..15 -> row groups
  const int tx = t & 15;          // 0..15 -> col groups
  const size_t m0 = (size_t)blockIdx.x * 128;

  float acc[8][CPT];
#pragma unroll
  for (int i = 0; i < 8; i++)
#pragma unroll
    for (int jj = 0; jj < CPT; jj++) acc[i][jj] = 0.f;

  const int mload = t >> 3;        // 0..31
  const int kf = (t & 7) << 2;     // 0,4,...,28

  for (int kc = 0; kc < 128; kc += KC) {
#pragma unroll
    for (int q = 0; q < 4; q++) {
      const int m = mload + 32 * q;
      const float4 g = *(const float4*)(A + (m0 + m) * 128 + kc + kf);
      As[kf + 0][m] = g.x;
      As[kf + 1][m] = g.y;
      As[kf + 2][m] = g.z;
      As[kf + 3][m] = g.w;
    }
#pragma unroll
    for (int q = 0; q < (KC * DOUT) / 1024; q++) {
      const int idx = (t + q * 256) << 2;
      const int kk = idx / DOUT;
      const int j = idx % DOUT;
      *(float4*)(&Ws[kk][j]) = *(const float4*)(W + (size_t)(kc + kk) * DOUT + j);
    }
    __syncthreads();

#pragma unroll
    for (int kk = 0; kk < KC; kk++) {
      float a[8], w[CPT];
#pragma unroll
      for (int v = 0; v < 4; v++) {
        a[v] = As[kk][ty * 4 + v];
        a[4 + v] = As[kk][64 + ty * 4 + v];
      }
#pragma unroll
      for (int v = 0; v < 4; v++) {
        w[v] = Ws[kk][tx * 4 + v];
        if constexpr (CPT == 8) w[4 + v] = Ws[kk][64 + tx * 4 + v];
      }
#pragma unroll
      for (int i = 0; i < 8; i++)
#pragma unroll
        for (int jj = 0; jj < CPT; jj++) acc[i][jj] += a[i] * w[jj];
    }
    __syncthreads();
  }

#pragma unroll
  for (int i = 0; i < 8; i++) {
    const int m = (i < 4) ? (ty * 4 + i) : (64 + ty * 4 + (i - 4));
    float* orow = S + (m0 + m) * DOUT;
    float4 o;
    o.x = acc[i][0]; o.y = acc[i][1]; o.z = acc[i][2]; o.w = acc[i][3];
    *(float4*)(orow + tx * 4) = o;
    if constexpr (CPT == 8) {
      float4 o2;
      o2.x = acc[i][4]; o2.y = acc[i][5]; o2.z = acc[i][6]; o2.w = acc[i][7];
      *(float4*)(orow + 64 + tx * 4) = o2;
    }
  }
}

// ---------------------------------------------------------------------------
// Batch-sliced SpMM + bias + (residual) + relu + (sigmoid).
// grid = (NN/4, NB); 4 waves/block, one wave per (row r, batch b).
// Dispatch is x-fastest, so concurrently-resident blocks share ONE batch
// slice of S (25.6 MB) -> slice stays hot in LLC, HBM fetch ~= S once.
// Edge cols/vals are loaded 64-wide per wave and broadcast via __shfl.
// out/resid deliberately NOT __restrict__ (layer 2 runs in-place; each wave
// only reads/writes its own output row).
// ---------------------------------------------------------------------------
template <int DOUT, bool RESID, bool SIGMOID>
__global__ __launch_bounds__(256) void spmm_kernel(const float* __restrict__ S,
                                                   const int* __restrict__ row_ptr,
                                                   const int* __restrict__ cols,
                                                   const float* __restrict__ vals,
                                                   const float* __restrict__ bias,
                                                   const float* resid,
                                                   float* out) {
  constexpr int VEC = DOUT / 64;  // floats per lane: 2 (DOUT=128) or 1 (DOUT=64)
  typedef float vec_t __attribute__((ext_vector_type(VEC)));

  const int wave = threadIdx.x >> 6;
  const int lane = threadIdx.x & 63;
  const int r = blockIdx.x * 4 + wave;   // NN % 4 == 0, always in range
  const int b = blockIdx.y;
  const int j = lane * VEC;
  const float* Sb = S + (size_t)b * NN * DOUT + j;  // batch slice base + lane col

  vec_t acc;
#pragma unroll
  for (int v = 0; v < VEC; v++) acc[v] = 0.f;

  const int e0 = row_ptr[r];
  const int e1 = row_ptr[r + 1];

  for (int e = e0; e < e1; e += 64) {
    const int n = min(64, e1 - e);
    int c = 0;
    float w = 0.f;
    if (lane < n) {
      c = cols[e + lane];
      w = vals[e + lane];
    }
    int i = 0;
    for (; i + 4 <= n; i += 4) {
      const int c0 = __shfl(c, i + 0), c1 = __shfl(c, i + 1);
      const int c2 = __shfl(c, i + 2), c3 = __shfl(c, i + 3);
      const float w0 = __shfl(w, i + 0), w1 = __shfl(w, i + 1);
      const float w2 = __shfl(w, i + 2), w3 = __shfl(w, i + 3);
      const vec_t g0 = *(const vec_t*)(Sb + (size_t)c0 * DOUT);
      const vec_t g1 = *(const vec_t*)(Sb + (size_t)c1 * DOUT);
      const vec_t g2 = *(const vec_t*)(Sb + (size_t)c2 * DOUT);
      const vec_t g3 = *(const vec_t*)(Sb + (size_t)c3 * DOUT);
      acc += w0 * g0;
      acc += w1 * g1;
      acc += w2 * g2;
      acc += w3 * g3;
    }
    for (; i < n; i++) {
      const int ci = __shfl(c, i);
      const float wi = __shfl(w, i);
      const vec_t g = *(const vec_t*)(Sb + (size_t)ci * DOUT);
      acc += wi * g;
    }
  }

  // epilogue: bias + residual + relu (+ sigmoid), write own row
  const size_t orow = (size_t)(b * NN + r) * DOUT + j;
  const vec_t bb = *(const vec_t*)(bias + j);
  acc += bb;
  if constexpr (RESID) {
    const vec_t res = *(const vec_t*)(resid + orow);
    acc += res;
  }
#pragma unroll
  for (int v = 0; v < VEC; v++) {
    float o = fmaxf(acc[v], 0.f);
    if constexpr (SIGMOID) o = 1.f / (1.f + __expf(-o));
    acc[v] = o;
  }
  *(vec_t*)(out + orow) = acc;
}

// ---------------------------------------------------------------------------
// Launch: rowptr, then 3x (gemm -> spmm). Ping-pong buffers in d_ws.
// ws usage: 256 KiB + 2 * 204.8 MB ~= 410 MB.
// ---------------------------------------------------------------------------
extern "C" void kernel_launch(void* const* d_in, const int* in_sizes, int n_in,
                              void* d_out, int out_size, void* d_ws, size_t ws_size,
                              hipStream_t stream) {
  const float* x = (const float*)d_in[0];
  const int* erows = (const int*)d_in[1];
  const int* ecols = (const int*)d_in[2];
  const float* evals = (const float*)d_in[3];
  const float* W1 = (const float*)d_in[4];
  const float* b1 = (const float*)d_in[5];
  const float* W2 = (const float*)d_in[6];
  const float* b2 = (const float*)d_in[7];
  const float* W3 = (const float*)d_in[8];
  const float* b3 = (const float*)d_in[9];

  char* ws = (char*)d_ws;
  int* row_ptr = (int*)ws;
  float* bufA = (float*)(ws + (1 << 18));
  float* bufB = (float*)(ws + (1 << 18) + (size_t)M_ROWS * 128 * 4);

  rowptr_kernel<<<(NN + 256) / 256, 256, 0, stream>>>(erows, row_ptr);

  const dim3 sgrid(NN / 4, NB);

  // Layer 1: S = x@W1; H1 = relu(spmm(S) + b1 + x)
  gemm_kernel<128><<<M_ROWS / 128, 256, 0, stream>>>(x, W1, bufA);
  spmm_kernel<128, true, false><<<sgrid, 256, 0, stream>>>(bufA, row_ptr, ecols,
                                                           evals, b1, x, bufB);
  // Layer 2: S = H1@W2; H2 = relu(spmm(S) + b2 + H1)  (in place on bufB)
  gemm_kernel<128><<<M_ROWS / 128, 256, 0, stream>>>(bufB, W2, bufA);
  spmm_kernel<128, true, false><<<sgrid, 256, 0, stream>>>(bufA, row_ptr, ecols,
                                                           evals, b2, bufB, bufB);
  // Layer 3: S = H2@W3; out = sigmoid(relu(spmm(S) + b3))
  gemm_kernel<64><<<M_ROWS / 128, 256, 0, stream>>>(bufB, W3, bufA);
  spmm_kernel<64, false, true><<<sgrid, 256, 0, stream>>>(bufA, row_ptr, ecols,
                                                          evals, b3, nullptr,
                                                          (float*)d_out);
}

// Round 3
// 1545.926 us; speedup vs baseline: 1.9678x; 1.7384x over previous
//
#include <hip/hip_runtime.h>

// Problem constants (match reference setup_inputs)
constexpr int NN = 50000;        // nodes
constexpr int NE = 1600000;      // edges
constexpr int NB = 8;            // batch
constexpr int M_ROWS = NN * NB;  // 400000 flattened rows (m = b*NN + n)

typedef unsigned short ushort;
typedef unsigned int uint;

__device__ __forceinline__ ushort f2bf(float f) {
  union { float f; uint u; } v;
  v.f = f;
  const uint r = v.u + 0x7fffu + ((v.u >> 16) & 1u);  // RNE
  return (ushort)(r >> 16);
}
__device__ __forceinline__ float bfhi(uint g) {  // high bf16 of a dword
  union { uint u; float f; } v;
  v.u = g & 0xffff0000u;
  return v.f;
}
__device__ __forceinline__ float bflo(uint g) {  // low bf16 of a dword
  union { uint u; float f; } v;
  v.u = g << 16;
  return v.f;
}

// ---------------------------------------------------------------------------
// CSR row_ptr from sorted edge_rows via per-row binary search (lower_bound).
// ---------------------------------------------------------------------------
__global__ __launch_bounds__(256) void rowptr_kernel(const int* __restrict__ rows,
                                                     int* __restrict__ row_ptr) {
  const int r = blockIdx.x * 256 + threadIdx.x;
  if (r > NN) return;
  int lo = 0, hi = NE;
  while (lo < hi) {
    const int mid = (lo + hi) >> 1;
    if (rows[mid] < r) lo = mid + 1;
    else hi = mid;
  }
  row_ptr[r] = lo;
}

// ---------------------------------------------------------------------------
// W [128][DOUT] fp32 -> Wt [DOUT][128] bf16 (tiny, once per launch).
// ---------------------------------------------------------------------------
__global__ __launch_bounds__(256) void wtrans_kernel(const float* __restrict__ W,
                                                     ushort* __restrict__ Wt,
                                                     int dout) {
  const int idx = blockIdx.x * 256 + threadIdx.x;  // over dout*128
  if (idx >= dout * 128) return;
  const int n = idx >> 7;
  const int k = idx & 127;
  Wt[idx] = f2bf(W[k * dout + n]);
}

// ---------------------------------------------------------------------------
// MFMA GEMM: S[M][DOUT] (bf16) = A[M][128] (fp32, converted in-kernel) @ W.
// Wt is pre-transposed bf16 [DOUT][128]. Block = 256 thr = 4 waves, 64 rows.
// K=128 staged once in LDS (row stride 136 -> b128 frag reads are 2-way,
// i.e. free per m136). mfma_f32_16x16x32_bf16:
//   A frag: lane holds A[m=lane&15][k=(lane>>4)*8 + j]   (m120/m89 verified)
//   B frag: lane holds B[k=(lane>>4)*8 + j][n=lane&15]
//   C/D:    col=lane&15, row=(lane>>4)*4+reg             (m89 verified)
// Epilogue round-trips through LDS (reusing As) for coalesced dwordx4 stores.
// ---------------------------------------------------------------------------
template <int DOUT>
__global__ __launch_bounds__(256) void gemm_mfma(const float* __restrict__ A,
                                                 const ushort* __restrict__ Wt,
                                                 ushort* __restrict__ S) {
  constexpr int NT = DOUT / 16;   // n-tiles per wave
  constexpr int LDK = 136;        // padded LDS row stride (ushorts); 272 B, 16B-aligned
  typedef __attribute__((ext_vector_type(8))) short bf16x8;
  typedef __attribute__((ext_vector_type(4))) float f32x4;

  __shared__ ushort As[64 * LDK];
  __shared__ ushort Ws[DOUT * LDK];

  const int t = threadIdx.x;
  const int w = t >> 6;
  const int l = t & 63;
  const size_t m0 = (size_t)blockIdx.x * 64;

  // ---- stage A tile: 64 rows x 128 fp32 -> bf16 LDS ----
  {
    const int row = t >> 2;
    const int c0 = (t & 3) * 32;
    const float* src = A + (m0 + row) * 128 + c0;
    ushort* dst = As + row * LDK + c0;
#pragma unroll
    for (int q = 0; q < 8; q++) {
      const float4 g = *(const float4*)(src + q * 4);
      dst[q * 4 + 0] = f2bf(g.x);
      dst[q * 4 + 1] = f2bf(g.y);
      dst[q * 4 + 2] = f2bf(g.z);
      dst[q * 4 + 3] = f2bf(g.w);
    }
  }
  // ---- stage Wt: DOUT x 128 bf16 -> LDS (16B chunks, coalesced) ----
  {
#pragma unroll
    for (int q = 0; q < (DOUT * 128) / (8 * 256); q++) {
      const int chunk = t + q * 256;
      const int n = chunk >> 4;
      const int off = (chunk & 15) * 8;
      *(uint4*)(Ws + n * LDK + off) = *(const uint4*)(Wt + n * 128 + off);
    }
  }
  __syncthreads();

  // ---- K loop (fully unrolled; K=128 = 4 mfma steps) ----
  const int mrow = w * 16 + (l & 15);
  const int q8 = (l >> 4) * 8;

  bf16x8 a[4];
  const ushort* ap = As + mrow * LDK + q8;
#pragma unroll
  for (int ks = 0; ks < 4; ks++) a[ks] = *(const bf16x8*)(ap + ks * 32);

  f32x4 acc[NT];
#pragma unroll
  for (int nt = 0; nt < NT; nt++) acc[nt] = (f32x4)0.f;

#pragma unroll
  for (int nt = 0; nt < NT; nt++) {
    const ushort* bp = Ws + (nt * 16 + (l & 15)) * LDK + q8;
#pragma unroll
    for (int ks = 0; ks < 4; ks++) {
      const bf16x8 b = *(const bf16x8*)(bp + ks * 32);
      acc[nt] = __builtin_amdgcn_mfma_f32_16x16x32_bf16(a[ks], b, acc[nt], 0, 0, 0);
    }
  }

  // ---- epilogue: acc -> LDS (bf16) -> coalesced global stores ----
  __syncthreads();  // all waves done reading As before overwrite
  const int erow = w * 16 + (l >> 4) * 4;
  const int ecol = l & 15;
#pragma unroll
  for (int nt = 0; nt < NT; nt++)
#pragma unroll
    for (int r = 0; r < 4; r++)
      As[(erow + r) * LDK + nt * 16 + ecol] = f2bf(acc[nt][r]);
  __syncthreads();

#pragma unroll
  for (int q = 0; q < (64 * DOUT) / (8 * 256); q++) {
    const int chunk = t + q * 256;
    const int row = chunk / (DOUT / 8);
    const int off = (chunk % (DOUT / 8)) * 8;
    *(uint4*)(S + (m0 + row) * DOUT + off) = *(const uint4*)(As + row * LDK + off);
  }
}

// ---------------------------------------------------------------------------
// Batch-sliced SpMM over bf16 S + fp32 bias/residual/relu/sigmoid epilogue.
// grid = (NN/4, NB); one wave per (row r, batch b); x-fastest dispatch keeps
// the in-flight window inside one 12.8 MB batch slice of S.
// DOUT=128: lane loads 1 dword (2 bf16) per edge -> 256 B coalesced gather.
// DOUT=64:  lane loads 1 ushort per edge -> 128 B coalesced gather.
// out/resid NOT __restrict__ (layer 2 in-place; wave only touches own row).
// ---------------------------------------------------------------------------
template <int DOUT, bool RESID, bool SIGMOID>
__global__ __launch_bounds__(256) void spmm_kernel(const ushort* __restrict__ S,
                                                   const int* __restrict__ row_ptr,
                                                   const int* __restrict__ cols,
                                                   const float* __restrict__ vals,
                                                   const float* __restrict__ bias,
                                                   const float* resid,
                                                   float* out) {
  constexpr int VEC = DOUT / 64;  // fp32 outputs per lane: 2 or 1

  const int wave = threadIdx.x >> 6;
  const int lane = threadIdx.x & 63;
  const int r = blockIdx.x * 4 + wave;  // NN % 4 == 0
  const int b = blockIdx.y;
  const int j = lane * VEC;
  const ushort* Sb = S + (size_t)b * NN * DOUT + j;  // + c*DOUT for column c

  float acc0 = 0.f, acc1 = 0.f;

  const int e0 = row_ptr[r];
  const int e1 = row_ptr[r + 1];

  for (int e = e0; e < e1; e += 64) {
    const int n = min(64, e1 - e);
    int c = 0;
    float wv = 0.f;
    if (lane < n) {
      c = cols[e + lane];
      wv = vals[e + lane];
    }
    int i = 0;
    for (; i + 4 <= n; i += 4) {
      const int c0 = __shfl(c, i + 0), c1 = __shfl(c, i + 1);
      const int c2 = __shfl(c, i + 2), c3 = __shfl(c, i + 3);
      const float w0 = __shfl(wv, i + 0), w1 = __shfl(wv, i + 1);
      const float w2 = __shfl(wv, i + 2), w3 = __shfl(wv, i + 3);
      if constexpr (VEC == 2) {
        const uint g0 = *(const uint*)(Sb + (size_t)c0 * DOUT);
        const uint g1 = *(const uint*)(Sb + (size_t)c1 * DOUT);
        const uint g2 = *(const uint*)(Sb + (size_t)c2 * DOUT);
        const uint g3 = *(const uint*)(Sb + (size_t)c3 * DOUT);
        acc0 += w0 * bflo(g0); acc1 += w0 * bfhi(g0);
        acc0 += w1 * bflo(g1); acc1 += w1 * bfhi(g1);
        acc0 += w2 * bflo(g2); acc1 += w2 * bfhi(g2);
        acc0 += w3 * bflo(g3); acc1 += w3 * bfhi(g3);
      } else {
        const ushort g0 = Sb[(size_t)c0 * DOUT];
        const ushort g1 = Sb[(size_t)c1 * DOUT];
        const ushort g2 = Sb[(size_t)c2 * DOUT];
        const ushort g3 = Sb[(size_t)c3 * DOUT];
        acc0 += w0 * bflo(g0);
        acc0 += w1 * bflo(g1);
        acc0 += w2 * bflo(g2);
        acc0 += w3 * bflo(g3);
      }
    }
    for (; i < n; i++) {
      const int ci = __shfl(c, i);
      const float wi = __shfl(wv, i);
      if constexpr (VEC == 2) {
        const uint g = *(const uint*)(Sb + (size_t)ci * DOUT);
        acc0 += wi * bflo(g); acc1 += wi * bfhi(g);
      } else {
        acc0 += wi * bflo(Sb[(size_t)ci * DOUT]);
      }
    }
  }

  // epilogue: bias + residual + relu (+ sigmoid), write own row (fp32)
  const size_t orow = (size_t)(b * NN + r) * DOUT + j;
  if constexpr (VEC == 2) {
    acc0 += bias[j + 0];
    acc1 += bias[j + 1];
    if constexpr (RESID) {
      const float2 res = *(const float2*)(resid + orow);
      acc0 += res.x; acc1 += res.y;
    }
    acc0 = fmaxf(acc0, 0.f); acc1 = fmaxf(acc1, 0.f);
    if constexpr (SIGMOID) {
      acc0 = 1.f / (1.f + __expf(-acc0));
      acc1 = 1.f / (1.f + __expf(-acc1));
    }
    float2 o; o.x = acc0; o.y = acc1;
    *(float2*)(out + orow) = o;
  } else {
    acc0 += bias[j];
    if constexpr (RESID) acc0 += resid[orow];
    acc0 = fmaxf(acc0, 0.f);
    if constexpr (SIGMOID) acc0 = 1.f / (1.f + __expf(-acc0));
    out[orow] = acc0;
  }
}

// ---------------------------------------------------------------------------
// Launch. ws layout: row_ptr (256 KiB) | Wt1,Wt2,Wt3 bf16 (to 0x60000) |
// S bf16 102.4 MB | H fp32 204.8 MB.  ~308 MB total.
// ---------------------------------------------------------------------------
extern "C" void kernel_launch(void* const* d_in, const int* in_sizes, int n_in,
                              void* d_out, int out_size, void* d_ws, size_t ws_size,
                              hipStream_t stream) {
  const float* x = (const float*)d_in[0];
  const int* erows = (const int*)d_in[1];
  const int* ecols = (const int*)d_in[2];
  const float* evals = (const float*)d_in[3];
  const float* W1 = (const float*)d_in[4];
  const float* b1 = (const float*)d_in[5];
  const float* W2 = (const float*)d_in[6];
  const float* b2 = (const float*)d_in[7];
  const float* W3 = (const float*)d_in[8];
  const float* b3 = (const float*)d_in[9];

  char* ws = (char*)d_ws;
  int* row_ptr = (int*)ws;
  ushort* Wt1 = (ushort*)(ws + 0x40000);
  ushort* Wt2 = (ushort*)(ws + 0x48000);
  ushort* Wt3 = (ushort*)(ws + 0x50000);
  ushort* Sbf = (ushort*)(ws + 0x60000);
  float* H = (float*)(ws + 0x60000 + (size_t)M_ROWS * 128 * 2);

  rowptr_kernel<<<(NN + 256) / 256, 256, 0, stream>>>(erows, row_ptr);
  wtrans_kernel<<<(128 * 128) / 256, 256, 0, stream>>>(W1, Wt1, 128);
  wtrans_kernel<<<(128 * 128) / 256, 256, 0, stream>>>(W2, Wt2, 128);
  wtrans_kernel<<<(64 * 128) / 256, 256, 0, stream>>>(W3, Wt3, 64);

  const dim3 sgrid(NN / 4, NB);

  // Layer 1: S = x@W1; H = relu(spmm(S) + b1 + x)
  gemm_mfma<128><<<M_ROWS / 64, 256, 0, stream>>>(x, Wt1, Sbf);
  spmm_kernel<128, true, false><<<sgrid, 256, 0, stream>>>(Sbf, row_ptr, ecols,
                                                           evals, b1, x, H);
  // Layer 2: S = H@W2; H = relu(spmm(S) + b2 + H)  (in place)
  gemm_mfma<128><<<M_ROWS / 64, 256, 0, stream>>>(H, Wt2, Sbf);
  spmm_kernel<128, true, false><<<sgrid, 256, 0, stream>>>(Sbf, row_ptr, ecols,
                                                           evals, b2, H, H);
  // Layer 3: S = H@W3; out = sigmoid(relu(spmm(S) + b3))
  gemm_mfma<64><<<M_ROWS / 64, 256, 0, stream>>>(H, Wt3, Sbf);
  spmm_kernel<64, false, true><<<sgrid, 256, 0, stream>>>(Sbf, row_ptr, ecols,
                                                          evals, b3, nullptr,
                                                          (float*)d_out);
}